// Round 7
// baseline (83.482 us; speedup 1.0000x reference)
//
#include <hip/hip_runtime.h>
#include <math.h>

// Problem constants (from reference): DT=1, V_LAMBDA=1e-4, V_RIDGE=1e-4
#define LAM3  1e-4f   // V_LAMBDA / DT^6
#define RIDGE 1e-4f
#define NN    64      // N
#define NP    65      // N+1

// INSTRUMENTED PROBE ROUND: run the identical r6 body REP times per launch so
// the dispatch exceeds the ~41us fill kernels and surfaces in the rocprof
// top-5 with its own counters (VGPR/VALUBusy/LDS-conflict/FETCH). Stores are
// idempotent; a memory clobber per rep forces a faithful full replica
// (including input reloads). REP=1 restores the production kernel.
#define REP 4

// (D3^T D3) band values for Np=65 (third-difference smoother), boundary-truncated.
__device__ __forceinline__ float d3_diag(int f) {
    if (f == 0 || f == 64) return 1.f;
    if (f == 1 || f == 63) return 10.f;
    if (f == 2 || f == 62) return 19.f;
    return 20.f;
}
__device__ __forceinline__ float d3_off1(int f) { // [f][f-1], valid f>=1
    if (f == 1 || f == 64) return -3.f;
    if (f == 2 || f == 63) return -12.f;
    return -15.f;
}
__device__ __forceinline__ float d3_off2(int f) { // [f][f-2], valid f>=2
    if (f == 2 || f == 64) return 3.f;
    return 6.f;
}
// [f][f-3] == -1 everywhere it exists (f>=3)

__global__ __launch_bounds__(64, 1) void alpamayo_banded_solve(
    const float* __restrict__ dxy,    // [B,64,2]
    const float* __restrict__ theta,  // [B,65]
    const float* __restrict__ v0,     // [B]
    float* __restrict__ out,          // [B,65]
    int B)
{
    // Per-thread column layout: no cross-thread sharing -> no barriers needed.
    __shared__ float4 Lrec[NN][64];   // 64 KiB

    const int tid = threadIdx.x;
    const int b = blockIdx.x * 64 + tid;
    if (b >= B) return;

    #pragma unroll 1
    for (int rep = 0; rep < REP; ++rep) {
        asm volatile("" ::: "memory");   // faithful re-execution each rep

        const float* th = theta + (long)b * NP;
        const float4* dx4 = (const float4*)(dxy + (long)b * (2 * NN));
        const float v0b = v0[b];

        // ---- Preload ALL inputs into registers (batched, one vmcnt drain) ----
        float dxf[2 * NN];
        #pragma unroll
        for (int j = 0; j < 32; ++j) {
            const float4 q = dx4[j];
            dxf[4 * j + 0] = q.x; dxf[4 * j + 1] = q.y;
            dxf[4 * j + 2] = q.z; dxf[4 * j + 3] = q.w;
        }
        float thr[NP];
        #pragma unroll
        for (int f = 0; f < NP; ++f) thr[f] = th[f];

        float* outp = out + (long)b * NP;
        outp[0] = v0b;                       // fire early, off-chain

        // ---- FUSED: sincos + e + rhs + banded Cholesky + forward substitution ----
        float z[NN];
        float cp, sp;
        __sincosf(thr[0], &sp, &cp);
        float xc = dxf[0], yc = dxf[1];

        float p1L1 = 0.f, p1L2 = 0.f, p2L1 = 0.f;
        float rd1 = 0.f, rd2 = 0.f, rd3 = 0.f;
        float z1 = 0.f, z2 = 0.f, z3 = 0.f;

        #pragma unroll
        for (int i = 0; i < NN; ++i) {
            const int f = i + 1;
            float cf, sf;
            __sincosf(thr[f], &sf, &cf);
            const float e  = cf * cp + sf * sp;            // cos(theta_f - theta_{f-1})
            const float xs = (f < NN) ? dxf[2 * f]     : 0.f;
            const float ys = (f < NN) ? dxf[2 * f + 1] : 0.f;
            float rr = 2.f * (cf * (xc + xs) + sf * (yc + ys));
            // v0 corrections, compile-time selected by the unroll.
            if (i == 0) rr -= (e + LAM3 * -3.f) * v0b;
            if (i == 1) rr -= (LAM3 *  3.f) * v0b;
            if (i == 2) rr -= (LAM3 * -1.f) * v0b;

            const float a0 = (f == NN ? 1.f : 2.f) + LAM3 * d3_diag(f) + RIDGE;
            const float a1 = e + LAM3 * d3_off1(f);
            const float a2 = LAM3 * d3_off2(f);

            const float Li3 = (-LAM3) * rd3;               // killed by rd3=0 for i<3
            const float Li2 = (a2 - Li3 * p2L1) * rd2;     // killed by rd2=0 for i<2
            const float Li1 = (a1 - Li3 * p1L2 - Li2 * p1L1) * rd1;
            const float dg  = a0 - Li3 * Li3 - Li2 * Li2 - Li1 * Li1;
            const float rd0 = __builtin_amdgcn_rsqf(dg);
            const float zi  = (rr - Li3 * z3 - Li2 * z2 - Li1 * z1) * rd0;

            Lrec[i][tid] = make_float4(Li1, Li2, Li3, rd0);
            z[i] = zi;

            p2L1 = p1L1; p1L1 = Li1; p1L2 = Li2;
            rd3 = rd2; rd2 = rd1; rd1 = rd0;
            z3 = z2; z2 = z1; z1 = zi;
            cp = cf; sp = sf; xc = xs; yc = ys;
        }

        // ---- Back substitution ----
        float r1L1 = 0.f, r1L2 = 0.f, r1L3 = 0.f;
        float r2L2 = 0.f, r2L3 = 0.f;
        float r3L3 = 0.f;
        float y1 = 0.f, y2 = 0.f, y3 = 0.f;

        #pragma unroll
        for (int i = NN - 1; i >= 0; --i) {
            const float4 rec = Lrec[i][tid];
            const float yi = (z[i] - r1L1 * y1 - r2L2 * y2 - r3L3 * y3) * rec.w;
            outp[1 + i] = yi;
            r3L3 = r2L3; r2L3 = r1L3; r2L2 = r1L2;
            r1L1 = rec.x; r1L2 = rec.y; r1L3 = rec.z;
            y3 = y2; y2 = y1; y1 = yi;
        }
    }
}

extern "C" void kernel_launch(void* const* d_in, const int* in_sizes, int n_in,
                              void* d_out, int out_size, void* d_ws, size_t ws_size,
                              hipStream_t stream) {
    const float* dxy   = (const float*)d_in[0];   // [B,64,2]
    const float* theta = (const float*)d_in[1];   // [B,65]
    const float* v0    = (const float*)d_in[2];   // [B]
    float* out = (float*)d_out;                   // [B,65]
    const int B = in_sizes[2];
    const int blocks = (B + 63) / 64;
    alpamayo_banded_solve<<<blocks, 64, 0, stream>>>(dxy, theta, v0, out, B);
}